// Round 1
// baseline (5819.588 us; speedup 1.0000x reference)
//
#include <hip/hip_runtime.h>
#include <hip/hip_bf16.h>

#define NN 20000
#define TT 16
#define EE 320000
#define CC 128
#define HH 128
#define PP 100000

// ---------------- CSR build ----------------

__global__ void hist_k(const int* __restrict__ dst, int* __restrict__ cnt) {
    int e = blockIdx.x * blockDim.x + threadIdx.x;
    if (e < EE) atomicAdd(&cnt[dst[e]], 1);
}

// single-block exclusive scan of cnt[NN] -> offs[NN+1]
__global__ __launch_bounds__(1024) void scan_k(const int* __restrict__ cnt,
                                               int* __restrict__ offs) {
    __shared__ int part[1024];
    int t = threadIdx.x;
    int base = t * 20;
    int vals[20];
    int s = 0;
#pragma unroll
    for (int i = 0; i < 20; ++i) {
        int idx = base + i;
        int v = (idx < NN) ? cnt[idx] : 0;
        vals[i] = v; s += v;
    }
    part[t] = s;
    __syncthreads();
    for (int off = 1; off < 1024; off <<= 1) {
        int v = (t >= off) ? part[t - off] : 0;
        __syncthreads();
        part[t] += v;
        __syncthreads();
    }
    int run = part[t] - s;   // exclusive prefix of this chunk
#pragma unroll
    for (int i = 0; i < 20; ++i) {
        int idx = base + i;
        if (idx < NN) offs[idx] = run;
        run += vals[i];
    }
    if (t == 0) offs[NN] = EE;
}

__global__ void dinv_k(const int* __restrict__ cnt, float* __restrict__ dinv,
                       int* __restrict__ cursor) {
    int i = blockIdx.x * blockDim.x + threadIdx.x;
    if (i < NN) {
        dinv[i] = rsqrtf((float)cnt[i] + 1.0f);  // deg includes self-loop
        cursor[i] = 0;
    }
}

__global__ void fill_k(const int* __restrict__ src, const int* __restrict__ dst,
                       const int* __restrict__ offs, int* __restrict__ cursor,
                       int* __restrict__ csr) {
    int e = blockIdx.x * blockDim.x + threadIdx.x;
    if (e < EE) {
        int d = dst[e];
        int p = atomicAdd(&cursor[d], 1);
        csr[offs[d] + p] = src[e];
    }
}

// ---------------- fp32 GEMM: C[M][NC] = A[M][128] @ B ----------------
// TRANSB=false: B is [128][NC] (GCN weights). TRANSB=true: B is [NC][128] (GRU w.T).
template <bool TRANSB>
__global__ __launch_bounds__(256) void gemm_k(const float* __restrict__ A,
                                              const float* __restrict__ B,
                                              float* __restrict__ Cout,
                                              int M, int NC) {
    __shared__ float As[64][64];  // As[k_local][row]
    __shared__ float Bs[64][64];  // Bs[k_local][col]
    int t = threadIdx.x;
    int row0 = blockIdx.x * 64, col0 = blockIdx.y * 64;
    int tx = t & 15, ty = t >> 4;
    int rr = ty * 4, cc = tx * 4;
    float acc[4][4] = {};

    for (int ks = 0; ks < 2; ++ks) {
        if (ks) __syncthreads();
        // stage A 64 rows x 64 k-cols (transposed into LDS)
#pragma unroll
        for (int pass = 0; pass < 4; ++pass) {
            int s = t + pass * 256;      // 0..1023
            int kq = s & 15, r = s >> 4; // kq: float4 within 64 cols
            int grow = row0 + r;
            float4 v = make_float4(0.f, 0.f, 0.f, 0.f);
            if (grow < M) v = *(const float4*)(A + (size_t)grow * 128 + ks * 64 + kq * 4);
            As[kq * 4 + 0][r] = v.x; As[kq * 4 + 1][r] = v.y;
            As[kq * 4 + 2][r] = v.z; As[kq * 4 + 3][r] = v.w;
        }
        // stage B 64 k x 64 cols
        if (TRANSB) {
#pragma unroll
            for (int pass = 0; pass < 4; ++pass) {
                int s = t + pass * 256;
                int kq = s & 15, c = s >> 4;
                float4 v = *(const float4*)(B + (size_t)(col0 + c) * 128 + ks * 64 + kq * 4);
                Bs[kq * 4 + 0][c] = v.x; Bs[kq * 4 + 1][c] = v.y;
                Bs[kq * 4 + 2][c] = v.z; Bs[kq * 4 + 3][c] = v.w;
            }
        } else {
#pragma unroll
            for (int pass = 0; pass < 4; ++pass) {
                int s = t + pass * 256;
                int c4 = s & 15, k = s >> 4;
                float4 v = *(const float4*)(B + (size_t)(ks * 64 + k) * NC + col0 + c4 * 4);
                *(float4*)&Bs[k][c4 * 4] = v;
            }
        }
        __syncthreads();
#pragma unroll 8
        for (int k = 0; k < 64; ++k) {
            float4 av = *(const float4*)&As[k][rr];
            float4 bv = *(const float4*)&Bs[k][cc];
            float a[4] = {av.x, av.y, av.z, av.w};
            float b[4] = {bv.x, bv.y, bv.z, bv.w};
#pragma unroll
            for (int i = 0; i < 4; ++i)
#pragma unroll
                for (int j = 0; j < 4; ++j)
                    acc[i][j] = fmaf(a[i], b[j], acc[i][j]);
        }
    }
#pragma unroll
    for (int i = 0; i < 4; ++i) {
        int grow = row0 + rr + i;
        if (grow < M) {
            float4 v = make_float4(acc[i][0], acc[i][1], acc[i][2], acc[i][3]);
            *(float4*)(Cout + (size_t)grow * NC + col0 + cc) = v;
        }
    }
}

// ---------------- GCN aggregation ----------------
// out[n] = dinv[n] * sum_{src in N(n)} dinv[src]*hlin[src] + dinv[n]^2*hlin[n] + b
__global__ __launch_bounds__(128) void agg_k(const float* __restrict__ hlin,
                                             const int* __restrict__ csr,
                                             const int* __restrict__ offs,
                                             const float* __restrict__ dinv,
                                             const float* __restrict__ bias,
                                             float* __restrict__ out, int relu) {
    int n = blockIdx.x;
    int h = threadIdx.x;
    int beg = offs[n], end = offs[n + 1];
    float acc = 0.f;
    for (int e = beg; e < end; ++e) {
        int s = csr[e];
        acc += dinv[s] * hlin[(size_t)s * HH + h];
    }
    float dn = dinv[n];
    float v = dn * acc + dn * dn * hlin[(size_t)n * HH + h] + bias[h];
    if (relu) v = fmaxf(v, 0.f);
    out[(size_t)n * HH + h] = v;
}

// ---------------- GRU gates (elementwise) ----------------
__global__ __launch_bounds__(256) void gru_gate_k(const float* __restrict__ gi,
                                                  const float* __restrict__ gh,
                                                  const float* __restrict__ b_ih,
                                                  const float* __restrict__ b_hh,
                                                  float* __restrict__ hgru) {
    int idx = blockIdx.x * blockDim.x + threadIdx.x;
    if (idx >= NN * HH) return;
    int n = idx >> 7, h = idx & 127;
    size_t base = (size_t)n * 384;
    float ir = gi[base + h]       + b_ih[h];
    float iz = gi[base + 128 + h] + b_ih[128 + h];
    float in_ = gi[base + 256 + h] + b_ih[256 + h];
    float hr = gh[base + h]       + b_hh[h];
    float hz = gh[base + 128 + h] + b_hh[128 + h];
    float hn = gh[base + 256 + h] + b_hh[256 + h];
    float r = 1.f / (1.f + __expf(-(ir + hr)));
    float z = 1.f / (1.f + __expf(-(iz + hz)));
    float nn = tanhf(in_ + r * hn);
    float hp = hgru[idx];
    hgru[idx] = (1.f - z) * nn + z * hp;
}

// ---------------- decode: out[p] = dot(h[s], h[d]) ----------------
__global__ __launch_bounds__(256) void decode_k(const float* __restrict__ hgru,
                                                const int* __restrict__ pairs,
                                                float* __restrict__ out) {
    int gid = blockIdx.x * blockDim.x + threadIdx.x;
    int w = gid >> 6;
    int lane = threadIdx.x & 63;
    if (w >= PP) return;
    int s = pairs[w], d = pairs[PP + w];
    const float* zs = hgru + (size_t)s * HH;
    const float* zd = hgru + (size_t)d * HH;
    float acc = zs[lane] * zd[lane] + zs[lane + 64] * zd[lane + 64];
#pragma unroll
    for (int off = 32; off > 0; off >>= 1) acc += __shfl_down(acc, off);
    if (lane == 0) out[w] = acc;
}

// ---------------- orchestration ----------------
static inline size_t align256(size_t x) { return (x + 255) & ~(size_t)255; }

extern "C" void kernel_launch(void* const* d_in, const int* in_sizes, int n_in,
                              void* d_out, int out_size, void* d_ws, size_t ws_size,
                              hipStream_t stream) {
    const float* x_seq      = (const float*)d_in[0];
    const int*   edge_index = (const int*)d_in[1];
    const int*   edge_pairs = (const int*)d_in[2];
    const float* W1 = (const float*)d_in[3];
    const float* b1 = (const float*)d_in[4];
    const float* W2 = (const float*)d_in[5];
    const float* b2 = (const float*)d_in[6];
    const float* W3 = (const float*)d_in[7];
    const float* b3 = (const float*)d_in[8];
    const float* w_ih = (const float*)d_in[9];
    const float* w_hh = (const float*)d_in[10];
    const float* b_ih = (const float*)d_in[11];
    const float* b_hh = (const float*)d_in[12];

    char* p = (char*)d_ws;
    int*   cnt    = (int*)p;    p += align256(NN * sizeof(int));
    int*   offs   = (int*)p;    p += align256((NN + 1) * sizeof(int));
    int*   cursor = (int*)p;    p += align256(NN * sizeof(int));
    float* dinv   = (float*)p;  p += align256(NN * sizeof(float));
    int*   csr    = (int*)p;    p += align256(EE * sizeof(int));
    float* hlin   = (float*)p;  p += align256((size_t)NN * HH * sizeof(float));
    float* bufA   = (float*)p;  p += align256((size_t)NN * HH * sizeof(float));
    float* bufB   = (float*)p;  p += align256((size_t)NN * HH * sizeof(float));
    float* hgru   = (float*)p;  p += align256((size_t)NN * HH * sizeof(float));
    float* gi     = (float*)p;  p += align256((size_t)NN * 3 * HH * sizeof(float));
    float* gh     = (float*)p;  p += align256((size_t)NN * 3 * HH * sizeof(float));

    hipMemsetAsync(hgru, 0, (size_t)NN * HH * sizeof(float), stream);

    dim3 g64((NN + 63) / 64, 2);
    dim3 g384((NN + 63) / 64, 6);

    for (int t = 0; t < TT; ++t) {
        const int* src = edge_index + (size_t)t * 2 * EE;
        const int* dst = src + EE;

        hipMemsetAsync(cnt, 0, NN * sizeof(int), stream);
        hist_k<<<(EE + 255) / 256, 256, 0, stream>>>(dst, cnt);
        scan_k<<<1, 1024, 0, stream>>>(cnt, offs);
        dinv_k<<<(NN + 255) / 256, 256, 0, stream>>>(cnt, dinv, cursor);
        fill_k<<<(EE + 255) / 256, 256, 0, stream>>>(src, dst, offs, cursor, csr);

        const float* xin = x_seq + (size_t)t * NN * CC;
        gemm_k<false><<<g64, 256, 0, stream>>>(xin, W1, hlin, NN, 128);
        agg_k<<<NN, 128, 0, stream>>>(hlin, csr, offs, dinv, b1, bufA, 1);
        gemm_k<false><<<g64, 256, 0, stream>>>(bufA, W2, hlin, NN, 128);
        agg_k<<<NN, 128, 0, stream>>>(hlin, csr, offs, dinv, b2, bufB, 1);
        gemm_k<false><<<g64, 256, 0, stream>>>(bufB, W3, hlin, NN, 128);
        agg_k<<<NN, 128, 0, stream>>>(hlin, csr, offs, dinv, b3, bufA, 0);  // feats_t

        gemm_k<true><<<g384, 256, 0, stream>>>(bufA, w_ih, gi, NN, 384);
        gemm_k<true><<<g384, 256, 0, stream>>>(hgru, w_hh, gh, NN, 384);
        gru_gate_k<<<(NN * HH + 255) / 256, 256, 0, stream>>>(gi, gh, b_ih, b_hh, hgru);
    }

    decode_k<<<(PP * 64 + 255) / 256, 256, 0, stream>>>(hgru, edge_pairs, (float*)d_out);
}

// Round 2
// 4320.567 us; speedup vs baseline: 1.3470x; 1.3470x over previous
//
#include <hip/hip_runtime.h>
#include <hip/hip_bf16.h>

#define NN 20000
#define TT 16
#define EE 320000
#define CC 128
#define HH 128
#define PP 100000

typedef __bf16 bf16x8 __attribute__((ext_vector_type(8)));
typedef float  f32x4  __attribute__((ext_vector_type(4)));
typedef unsigned short ushort4v __attribute__((ext_vector_type(4)));
typedef unsigned short ushort8v __attribute__((ext_vector_type(8)));

__device__ __forceinline__ unsigned short f2bf(float x) {
    union { float f; unsigned u; } v; v.f = x;
    unsigned r = v.u + 0x7FFF + ((v.u >> 16) & 1);
    return (unsigned short)(r >> 16);
}
__device__ __forceinline__ float bf2f(unsigned short h) {
    union { unsigned u; float f; } v; v.u = ((unsigned)h) << 16; return v.f;
}

// ---------------- CSR build ----------------

__global__ void hist_k(const int* __restrict__ dst, int* __restrict__ cnt) {
    int e = blockIdx.x * blockDim.x + threadIdx.x;
    if (e < EE) atomicAdd(&cnt[dst[e]], 1);
}

__global__ __launch_bounds__(1024) void scan_k(const int* __restrict__ cnt,
                                               int* __restrict__ offs) {
    __shared__ int part[1024];
    int t = threadIdx.x;
    int base = t * 20;
    int vals[20];
    int s = 0;
#pragma unroll
    for (int i = 0; i < 20; ++i) {
        int idx = base + i;
        int v = (idx < NN) ? cnt[idx] : 0;
        vals[i] = v; s += v;
    }
    part[t] = s;
    __syncthreads();
    for (int off = 1; off < 1024; off <<= 1) {
        int v = (t >= off) ? part[t - off] : 0;
        __syncthreads();
        part[t] += v;
        __syncthreads();
    }
    int run = part[t] - s;
#pragma unroll
    for (int i = 0; i < 20; ++i) {
        int idx = base + i;
        if (idx < NN) offs[idx] = run;
        run += vals[i];
    }
    if (t == 0) offs[NN] = EE;
}

__global__ void dinv_k(const int* __restrict__ cnt, float* __restrict__ dinv,
                       int* __restrict__ cursor) {
    int i = blockIdx.x * blockDim.x + threadIdx.x;
    if (i < NN) {
        dinv[i] = rsqrtf((float)cnt[i] + 1.0f);
        cursor[i] = 0;
    }
}

__global__ void fill_k(const int* __restrict__ src, const int* __restrict__ dst,
                       const int* __restrict__ offs, int* __restrict__ cursor,
                       int* __restrict__ csr) {
    int e = blockIdx.x * blockDim.x + threadIdx.x;
    if (e < EE) {
        int d = dst[e];
        int p = atomicAdd(&cursor[d], 1);
        csr[offs[d] + p] = src[e];
    }
}

// ---------------- weight prep: fp32 -> bf16 hi/lo ----------------
// transpose-convert: out[n*128+k] = W[k*128+n]  (W is [128][128])
__global__ void wprep_t_k(const float* __restrict__ W,
                          unsigned short* __restrict__ oh,
                          unsigned short* __restrict__ ol) {
    int i = blockIdx.x * blockDim.x + threadIdx.x;
    if (i >= 128 * 128) return;
    int n = i >> 7, k = i & 127;
    float v = W[k * 128 + n];
    unsigned short h = f2bf(v);
    oh[i] = h;
    ol[i] = f2bf(v - bf2f(h));
}

// direct convert (w is [NC][128] already row-per-output)
__global__ void wprep_d_k(const float* __restrict__ w,
                          unsigned short* __restrict__ oh,
                          unsigned short* __restrict__ ol, int n) {
    int i = blockIdx.x * blockDim.x + threadIdx.x;
    if (i >= n) return;
    float v = w[i];
    unsigned short h = f2bf(v);
    oh[i] = h;
    ol[i] = f2bf(v - bf2f(h));
}

// ---------------- split-bf16 MFMA GEMM ----------------
// C[M][NC] = A[M][128] @ B^T, where B given as bf16 hi/lo in [NC][128] layout.
// Split-precision: C = Ah*Bh + Ah*Bl + Al*Bh (fp32 accumulate) -> ~fp32 accuracy.
// Block tile 64x64, 4 waves of 32x32, BK=64 two-stage (LDS 36.9 KB -> 4 blocks/CU).
__global__ __launch_bounds__(256) void gemm_bf16s(const float* __restrict__ A,
                                                  const unsigned short* __restrict__ Bh,
                                                  const unsigned short* __restrict__ Bl,
                                                  float* __restrict__ C,
                                                  int M, int NC) {
    // row stride 72 bf16 = 144 B: 16B-aligned rows, 2-way (free) bank aliasing
    __shared__ unsigned short Ah[64 * 72];
    __shared__ unsigned short Al[64 * 72];
    __shared__ unsigned short Bhs[64 * 72];
    __shared__ unsigned short Bls[64 * 72];
    int t = threadIdx.x;
    int row0 = blockIdx.x * 64, col0 = blockIdx.y * 64;
    int w = t >> 6, lane = t & 63;
    int wm = (w & 1) * 32, wn = (w >> 1) * 32;
    int lm = lane & 15, lq = lane >> 4;
    f32x4 acc[2][2] = {};

    for (int ks = 0; ks < 2; ++ks) {
        if (ks) __syncthreads();
        // stage A (fp32 -> hi/lo bf16): 64 rows x 64 k
#pragma unroll
        for (int p = 0; p < 4; ++p) {
            int s = t + p * 256;
            int r = s >> 4, c4 = s & 15;
            int gr = row0 + r;
            float4 v = make_float4(0.f, 0.f, 0.f, 0.f);
            if (gr < M) v = *(const float4*)(A + (size_t)gr * 128 + ks * 64 + c4 * 4);
            ushort4v h, l;
            h.x = f2bf(v.x); h.y = f2bf(v.y); h.z = f2bf(v.z); h.w = f2bf(v.w);
            l.x = f2bf(v.x - bf2f(h.x)); l.y = f2bf(v.y - bf2f(h.y));
            l.z = f2bf(v.z - bf2f(h.z)); l.w = f2bf(v.w - bf2f(h.w));
            *(ushort4v*)&Ah[r * 72 + c4 * 4] = h;
            *(ushort4v*)&Al[r * 72 + c4 * 4] = l;
        }
        // stage B (already bf16 hi/lo, [NC][128]): 64 rows x 64 k
#pragma unroll
        for (int p = 0; p < 2; ++p) {
            int s = t + p * 256;
            int n = s >> 3, c = s & 7;
            *(ushort8v*)&Bhs[n * 72 + c * 8] =
                *(const ushort8v*)(Bh + (size_t)(col0 + n) * 128 + ks * 64 + c * 8);
            *(ushort8v*)&Bls[n * 72 + c * 8] =
                *(const ushort8v*)(Bl + (size_t)(col0 + n) * 128 + ks * 64 + c * 8);
        }
        __syncthreads();
#pragma unroll
        for (int q = 0; q < 2; ++q) {
            int ko = q * 32 + lq * 8;
            bf16x8 ah[2], al[2], bh[2], bl[2];
#pragma unroll
            for (int i = 0; i < 2; ++i) {
                ah[i] = *(const bf16x8*)&Ah[(wm + i * 16 + lm) * 72 + ko];
                al[i] = *(const bf16x8*)&Al[(wm + i * 16 + lm) * 72 + ko];
            }
#pragma unroll
            for (int j = 0; j < 2; ++j) {
                bh[j] = *(const bf16x8*)&Bhs[(wn + j * 16 + lm) * 72 + ko];
                bl[j] = *(const bf16x8*)&Bls[(wn + j * 16 + lm) * 72 + ko];
            }
#pragma unroll
            for (int i = 0; i < 2; ++i)
#pragma unroll
                for (int j = 0; j < 2; ++j) {
                    acc[i][j] = __builtin_amdgcn_mfma_f32_16x16x32_bf16(ah[i], bh[j], acc[i][j], 0, 0, 0);
                    acc[i][j] = __builtin_amdgcn_mfma_f32_16x16x32_bf16(ah[i], bl[j], acc[i][j], 0, 0, 0);
                    acc[i][j] = __builtin_amdgcn_mfma_f32_16x16x32_bf16(al[i], bh[j], acc[i][j], 0, 0, 0);
                }
        }
    }
    // epilogue: C/D layout col=lane&15, row=(lane>>4)*4+reg  [m89-verified]
#pragma unroll
    for (int i = 0; i < 2; ++i)
#pragma unroll
        for (int j = 0; j < 2; ++j)
#pragma unroll
            for (int reg = 0; reg < 4; ++reg) {
                int gr = row0 + wm + i * 16 + lq * 4 + reg;
                if (gr < M)
                    C[(size_t)gr * NC + col0 + wn + j * 16 + lm] = acc[i][j][reg];
            }
}

// ---------------- GCN aggregation ----------------
__global__ __launch_bounds__(128) void agg_k(const float* __restrict__ hlin,
                                             const int* __restrict__ csr,
                                             const int* __restrict__ offs,
                                             const float* __restrict__ dinv,
                                             const float* __restrict__ bias,
                                             float* __restrict__ out, int relu) {
    int n = blockIdx.x;
    int h = threadIdx.x;
    int beg = offs[n], end = offs[n + 1];
    float acc = 0.f;
    for (int e = beg; e < end; ++e) {
        int s = csr[e];
        acc += dinv[s] * hlin[(size_t)s * HH + h];
    }
    float dn = dinv[n];
    float v = dn * acc + dn * dn * hlin[(size_t)n * HH + h] + bias[h];
    if (relu) v = fmaxf(v, 0.f);
    out[(size_t)n * HH + h] = v;
}

// ---------------- GRU gates ----------------
__global__ __launch_bounds__(256) void gru_gate_k(const float* __restrict__ gi,
                                                  const float* __restrict__ gh,
                                                  const float* __restrict__ b_ih,
                                                  const float* __restrict__ b_hh,
                                                  float* __restrict__ hgru) {
    int idx = blockIdx.x * blockDim.x + threadIdx.x;
    if (idx >= NN * HH) return;
    int h = idx & 127;
    size_t base = (size_t)(idx >> 7) * 384;
    float ir = gi[base + h]        + b_ih[h];
    float iz = gi[base + 128 + h]  + b_ih[128 + h];
    float in_ = gi[base + 256 + h] + b_ih[256 + h];
    float hr = gh[base + h]        + b_hh[h];
    float hz = gh[base + 128 + h]  + b_hh[128 + h];
    float hn = gh[base + 256 + h]  + b_hh[256 + h];
    float r = 1.f / (1.f + __expf(-(ir + hr)));
    float z = 1.f / (1.f + __expf(-(iz + hz)));
    float nn = tanhf(in_ + r * hn);
    float hp = hgru[idx];
    hgru[idx] = (1.f - z) * nn + z * hp;
}

// ---------------- decode ----------------
__global__ __launch_bounds__(256) void decode_k(const float* __restrict__ hgru,
                                                const int* __restrict__ pairs,
                                                float* __restrict__ out) {
    int gid = blockIdx.x * blockDim.x + threadIdx.x;
    int w = gid >> 6;
    int lane = threadIdx.x & 63;
    if (w >= PP) return;
    int s = pairs[w], d = pairs[PP + w];
    const float* zs = hgru + (size_t)s * HH;
    const float* zd = hgru + (size_t)d * HH;
    float acc = zs[lane] * zd[lane] + zs[lane + 64] * zd[lane + 64];
#pragma unroll
    for (int off = 32; off > 0; off >>= 1) acc += __shfl_down(acc, off);
    if (lane == 0) out[w] = acc;
}

// ---------------- orchestration ----------------
static inline size_t align256(size_t x) { return (x + 255) & ~(size_t)255; }

extern "C" void kernel_launch(void* const* d_in, const int* in_sizes, int n_in,
                              void* d_out, int out_size, void* d_ws, size_t ws_size,
                              hipStream_t stream) {
    const float* x_seq      = (const float*)d_in[0];
    const int*   edge_index = (const int*)d_in[1];
    const int*   edge_pairs = (const int*)d_in[2];
    const float* W1 = (const float*)d_in[3];
    const float* b1 = (const float*)d_in[4];
    const float* W2 = (const float*)d_in[5];
    const float* b2 = (const float*)d_in[6];
    const float* W3 = (const float*)d_in[7];
    const float* b3 = (const float*)d_in[8];
    const float* w_ih = (const float*)d_in[9];
    const float* w_hh = (const float*)d_in[10];
    const float* b_ih = (const float*)d_in[11];
    const float* b_hh = (const float*)d_in[12];

    char* p = (char*)d_ws;
    int*   cnt    = (int*)p;    p += align256(NN * sizeof(int));
    int*   offs   = (int*)p;    p += align256((NN + 1) * sizeof(int));
    int*   cursor = (int*)p;    p += align256(NN * sizeof(int));
    float* dinv   = (float*)p;  p += align256(NN * sizeof(float));
    int*   csr    = (int*)p;    p += align256(EE * sizeof(int));
    float* hlin   = (float*)p;  p += align256((size_t)NN * HH * sizeof(float));
    float* bufA   = (float*)p;  p += align256((size_t)NN * HH * sizeof(float));
    float* bufB   = (float*)p;  p += align256((size_t)NN * HH * sizeof(float));
    float* hgru   = (float*)p;  p += align256((size_t)NN * HH * sizeof(float));
    float* gi     = (float*)p;  p += align256((size_t)NN * 3 * HH * sizeof(float));
    float* gh     = (float*)p;  p += align256((size_t)NN * 3 * HH * sizeof(float));
    // bf16 hi/lo weights
    unsigned short* W1h = (unsigned short*)p; p += align256(128 * 128 * 2);
    unsigned short* W1l = (unsigned short*)p; p += align256(128 * 128 * 2);
    unsigned short* W2h = (unsigned short*)p; p += align256(128 * 128 * 2);
    unsigned short* W2l = (unsigned short*)p; p += align256(128 * 128 * 2);
    unsigned short* W3h = (unsigned short*)p; p += align256(128 * 128 * 2);
    unsigned short* W3l = (unsigned short*)p; p += align256(128 * 128 * 2);
    unsigned short* wihh = (unsigned short*)p; p += align256(384 * 128 * 2);
    unsigned short* wihl = (unsigned short*)p; p += align256(384 * 128 * 2);
    unsigned short* whhh = (unsigned short*)p; p += align256(384 * 128 * 2);
    unsigned short* whhl = (unsigned short*)p; p += align256(384 * 128 * 2);

    hipMemsetAsync(hgru, 0, (size_t)NN * HH * sizeof(float), stream);

    wprep_t_k<<<64, 256, 0, stream>>>(W1, W1h, W1l);
    wprep_t_k<<<64, 256, 0, stream>>>(W2, W2h, W2l);
    wprep_t_k<<<64, 256, 0, stream>>>(W3, W3h, W3l);
    wprep_d_k<<<192, 256, 0, stream>>>(w_ih, wihh, wihl, 384 * 128);
    wprep_d_k<<<192, 256, 0, stream>>>(w_hh, whhh, whhl, 384 * 128);

    dim3 g128((NN + 63) / 64, 2);
    dim3 g384((NN + 63) / 64, 6);

    for (int t = 0; t < TT; ++t) {
        const int* src = edge_index + (size_t)t * 2 * EE;
        const int* dst = src + EE;

        hipMemsetAsync(cnt, 0, NN * sizeof(int), stream);
        hist_k<<<(EE + 255) / 256, 256, 0, stream>>>(dst, cnt);
        scan_k<<<1, 1024, 0, stream>>>(cnt, offs);
        dinv_k<<<(NN + 255) / 256, 256, 0, stream>>>(cnt, dinv, cursor);
        fill_k<<<(EE + 255) / 256, 256, 0, stream>>>(src, dst, offs, cursor, csr);

        const float* xin = x_seq + (size_t)t * NN * CC;
        gemm_bf16s<<<g128, 256, 0, stream>>>(xin, W1h, W1l, hlin, NN, 128);
        agg_k<<<NN, 128, 0, stream>>>(hlin, csr, offs, dinv, b1, bufA, 1);
        gemm_bf16s<<<g128, 256, 0, stream>>>(bufA, W2h, W2l, hlin, NN, 128);
        agg_k<<<NN, 128, 0, stream>>>(hlin, csr, offs, dinv, b2, bufB, 1);
        gemm_bf16s<<<g128, 256, 0, stream>>>(bufB, W3h, W3l, hlin, NN, 128);
        agg_k<<<NN, 128, 0, stream>>>(hlin, csr, offs, dinv, b3, bufA, 0);

        gemm_bf16s<<<g384, 256, 0, stream>>>(bufA, wihh, wihl, gi, NN, 384);
        gemm_bf16s<<<g384, 256, 0, stream>>>(hgru, whhh, whhl, gh, NN, 384);
        gru_gate_k<<<(NN * HH + 255) / 256, 256, 0, stream>>>(gi, gh, b_ih, b_hh, hgru);
    }

    decode_k<<<(PP * 64 + 255) / 256, 256, 0, stream>>>(hgru, edge_pairs, (float*)d_out);
}

// Round 3
// 2768.394 us; speedup vs baseline: 2.1022x; 1.5607x over previous
//
#include <hip/hip_runtime.h>
#include <hip/hip_bf16.h>

#define NN 20000
#define TT 16
#define EE 320000
#define CC 128
#define HH 128
#define PP 100000

typedef __bf16 bf16x8 __attribute__((ext_vector_type(8)));
typedef float  f32x4  __attribute__((ext_vector_type(4)));
typedef unsigned short ushort4v __attribute__((ext_vector_type(4)));
typedef unsigned short ushort8v __attribute__((ext_vector_type(8)));

__device__ __forceinline__ unsigned short f2bf(float x) {
    union { float f; unsigned u; } v; v.f = x;
    unsigned r = v.u + 0x7FFF + ((v.u >> 16) & 1);
    return (unsigned short)(r >> 16);
}
__device__ __forceinline__ float bf2f(unsigned short h) {
    union { unsigned u; float f; } v; v.u = ((unsigned)h) << 16; return v.f;
}

// ---------------- batched CSR build (all 16 frames in one dispatch each) ----------------

__global__ void hist_all_k(const int* __restrict__ edge_index, int* __restrict__ cnt_all) {
    int e = blockIdx.x * blockDim.x + threadIdx.x;
    int f = blockIdx.y;
    if (e < EE) {
        const int* dst = edge_index + (size_t)f * 2 * EE + EE;
        atomicAdd(&cnt_all[f * NN + dst[e]], 1);
    }
}

// 16 blocks, one per frame
__global__ __launch_bounds__(1024) void scan_all_k(const int* __restrict__ cnt_all,
                                                   int* __restrict__ offs_all) {
    __shared__ int part[1024];
    int f = blockIdx.x;
    const int* cnt = cnt_all + f * NN;
    int* offs = offs_all + f * (NN + 1);
    int t = threadIdx.x;
    int base = t * 20;
    int vals[20];
    int s = 0;
#pragma unroll
    for (int i = 0; i < 20; ++i) {
        int idx = base + i;
        int v = (idx < NN) ? cnt[idx] : 0;
        vals[i] = v; s += v;
    }
    part[t] = s;
    __syncthreads();
    for (int off = 1; off < 1024; off <<= 1) {
        int v = (t >= off) ? part[t - off] : 0;
        __syncthreads();
        part[t] += v;
        __syncthreads();
    }
    int run = part[t] - s;
#pragma unroll
    for (int i = 0; i < 20; ++i) {
        int idx = base + i;
        if (idx < NN) offs[idx] = run;
        run += vals[i];
    }
    if (t == 0) offs[NN] = EE;
}

__global__ void dinv_all_k(const int* __restrict__ cnt_all, float* __restrict__ dinv_all,
                           int* __restrict__ cursor_all) {
    int i = blockIdx.x * blockDim.x + threadIdx.x;
    int f = blockIdx.y;
    if (i < NN) {
        dinv_all[f * NN + i] = rsqrtf((float)cnt_all[f * NN + i] + 1.0f);
        cursor_all[f * NN + i] = 0;
    }
}

__global__ void fill_all_k(const int* __restrict__ edge_index,
                           const int* __restrict__ offs_all, int* __restrict__ cursor_all,
                           int* __restrict__ csr_all) {
    int e = blockIdx.x * blockDim.x + threadIdx.x;
    int f = blockIdx.y;
    if (e < EE) {
        const int* src = edge_index + (size_t)f * 2 * EE;
        const int* dst = src + EE;
        int d = dst[e];
        int p = atomicAdd(&cursor_all[f * NN + d], 1);
        csr_all[(size_t)f * EE + offs_all[f * (NN + 1) + d] + p] = src[e];
    }
}

// ---------------- weight prep: fp32 -> bf16 hi/lo ----------------
__global__ void wprep_t_k(const float* __restrict__ W,
                          unsigned short* __restrict__ oh,
                          unsigned short* __restrict__ ol) {
    int i = blockIdx.x * blockDim.x + threadIdx.x;
    if (i >= 128 * 128) return;
    int n = i >> 7, k = i & 127;
    float v = W[k * 128 + n];
    unsigned short h = f2bf(v);
    oh[i] = h;
    ol[i] = f2bf(v - bf2f(h));
}

__global__ void wprep_d_k(const float* __restrict__ w,
                          unsigned short* __restrict__ oh,
                          unsigned short* __restrict__ ol, int n) {
    int i = blockIdx.x * blockDim.x + threadIdx.x;
    if (i >= n) return;
    float v = w[i];
    unsigned short h = f2bf(v);
    oh[i] = h;
    ol[i] = f2bf(v - bf2f(h));
}

// ---------------- split-bf16 MFMA GEMM core ----------------
// C[M][NC] = (rowscale?) * (A[M][128] @ B^T), B as bf16 hi/lo in [NC][128].
// 3-MFMA split: Ah*Bh + Ah*Bl + Al*Bh, fp32 accum -> ~fp32 accuracy.
__device__ __forceinline__ void gemm_core(const float* __restrict__ A,
                                          const unsigned short* __restrict__ Bh,
                                          const unsigned short* __restrict__ Bl,
                                          float* __restrict__ C,
                                          const float* __restrict__ rowscale,
                                          int M, int NC, int row0, int col0,
                                          unsigned short* Ahs, unsigned short* Als,
                                          unsigned short* Bhs, unsigned short* Bls) {
    int t = threadIdx.x;
    int w = t >> 6, lane = t & 63;
    int wm = (w & 1) * 32, wn = (w >> 1) * 32;
    int lm = lane & 15, lq = lane >> 4;
    f32x4 acc[2][2] = {};

    for (int ks = 0; ks < 2; ++ks) {
        if (ks) __syncthreads();
#pragma unroll
        for (int p = 0; p < 4; ++p) {
            int s = t + p * 256;
            int r = s >> 4, c4 = s & 15;
            int gr = row0 + r;
            float4 v = make_float4(0.f, 0.f, 0.f, 0.f);
            if (gr < M) v = *(const float4*)(A + (size_t)gr * 128 + ks * 64 + c4 * 4);
            ushort4v h, l;
            h.x = f2bf(v.x); h.y = f2bf(v.y); h.z = f2bf(v.z); h.w = f2bf(v.w);
            l.x = f2bf(v.x - bf2f(h.x)); l.y = f2bf(v.y - bf2f(h.y));
            l.z = f2bf(v.z - bf2f(h.z)); l.w = f2bf(v.w - bf2f(h.w));
            *(ushort4v*)&Ahs[r * 72 + c4 * 4] = h;
            *(ushort4v*)&Als[r * 72 + c4 * 4] = l;
        }
#pragma unroll
        for (int p = 0; p < 2; ++p) {
            int s = t + p * 256;
            int n = s >> 3, c = s & 7;
            *(ushort8v*)&Bhs[n * 72 + c * 8] =
                *(const ushort8v*)(Bh + (size_t)(col0 + n) * 128 + ks * 64 + c * 8);
            *(ushort8v*)&Bls[n * 72 + c * 8] =
                *(const ushort8v*)(Bl + (size_t)(col0 + n) * 128 + ks * 64 + c * 8);
        }
        __syncthreads();
#pragma unroll
        for (int q = 0; q < 2; ++q) {
            int ko = q * 32 + lq * 8;
            bf16x8 ah[2], al[2], bh[2], bl[2];
#pragma unroll
            for (int i = 0; i < 2; ++i) {
                ah[i] = *(const bf16x8*)&Ahs[(wm + i * 16 + lm) * 72 + ko];
                al[i] = *(const bf16x8*)&Als[(wm + i * 16 + lm) * 72 + ko];
            }
#pragma unroll
            for (int j = 0; j < 2; ++j) {
                bh[j] = *(const bf16x8*)&Bhs[(wn + j * 16 + lm) * 72 + ko];
                bl[j] = *(const bf16x8*)&Bls[(wn + j * 16 + lm) * 72 + ko];
            }
#pragma unroll
            for (int i = 0; i < 2; ++i)
#pragma unroll
                for (int j = 0; j < 2; ++j) {
                    acc[i][j] = __builtin_amdgcn_mfma_f32_16x16x32_bf16(ah[i], bh[j], acc[i][j], 0, 0, 0);
                    acc[i][j] = __builtin_amdgcn_mfma_f32_16x16x32_bf16(ah[i], bl[j], acc[i][j], 0, 0, 0);
                    acc[i][j] = __builtin_amdgcn_mfma_f32_16x16x32_bf16(al[i], bh[j], acc[i][j], 0, 0, 0);
                }
        }
    }
    // C/D layout: col=lane&15, row=(lane>>4)*4+reg [m89-verified]
#pragma unroll
    for (int i = 0; i < 2; ++i)
#pragma unroll
        for (int reg = 0; reg < 4; ++reg) {
            int gr = row0 + wm + i * 16 + lq * 4 + reg;
            if (gr < M) {
                float sc = rowscale ? rowscale[gr] : 1.0f;
#pragma unroll
                for (int j = 0; j < 2; ++j)
                    C[(size_t)gr * NC + col0 + wn + j * 16 + lm] = sc * acc[i][j][reg];
            }
        }
}

__global__ __launch_bounds__(256) void gemm_bf16s(const float* __restrict__ A,
                                                  const unsigned short* __restrict__ Bh,
                                                  const unsigned short* __restrict__ Bl,
                                                  float* __restrict__ C,
                                                  const float* __restrict__ rowscale,
                                                  int M, int NC) {
    __shared__ unsigned short Ahs[64 * 72], Als[64 * 72], Bhs[64 * 72], Bls[64 * 72];
    gemm_core(A, Bh, Bl, C, rowscale, M, NC, blockIdx.x * 64, blockIdx.y * 64,
              Ahs, Als, Bhs, Bls);
}

// GRU: one dispatch computes both gi (from feats_t) and gh (from hgru)
__global__ __launch_bounds__(256) void gemm_gru_k(const float* __restrict__ Ft,
                                                  const float* __restrict__ hprev,
                                                  const unsigned short* __restrict__ wihh,
                                                  const unsigned short* __restrict__ wihl,
                                                  const unsigned short* __restrict__ whhh,
                                                  const unsigned short* __restrict__ whhl,
                                                  float* __restrict__ gi,
                                                  float* __restrict__ gh) {
    __shared__ unsigned short Ahs[64 * 72], Als[64 * 72], Bhs[64 * 72], Bls[64 * 72];
    int y = blockIdx.y;
    if (y < 6)
        gemm_core(Ft, wihh, wihl, gi, nullptr, NN, 384, blockIdx.x * 64, y * 64,
                  Ahs, Als, Bhs, Bls);
    else
        gemm_core(hprev, whhh, whhl, gh, nullptr, NN, 384, blockIdx.x * 64, (y - 6) * 64,
                  Ahs, Als, Bhs, Bls);
}

// ---------------- GCN aggregation (batched; HLs rows pre-scaled by dinv) ----------------
// out[n] = dinv[n] * (sum_{s in N(n)} HLs[s] + HLs[n]) + b
__global__ __launch_bounds__(128) void agg_all_k(const float* __restrict__ HLs,
                                                 const int* __restrict__ csr_all,
                                                 const int* __restrict__ offs_all,
                                                 const float* __restrict__ dinv_all,
                                                 const float* __restrict__ bias,
                                                 float* __restrict__ out, int relu) {
    int n = blockIdx.x;
    int f = blockIdx.y;
    int h = threadIdx.x;
    const int* offs = offs_all + f * (NN + 1);
    const int* csr = csr_all + (size_t)f * EE;
    const float* HL = HLs + (size_t)f * NN * HH;
    int beg = offs[n], end = offs[n + 1];
    float acc = 0.f;
    int e = beg;
    for (; e + 3 < end; e += 4) {
        int s0 = csr[e], s1 = csr[e + 1], s2 = csr[e + 2], s3 = csr[e + 3];
        float v0 = HL[(size_t)s0 * HH + h];
        float v1 = HL[(size_t)s1 * HH + h];
        float v2 = HL[(size_t)s2 * HH + h];
        float v3 = HL[(size_t)s3 * HH + h];
        acc += (v0 + v1) + (v2 + v3);
    }
    for (; e < end; ++e)
        acc += HL[(size_t)csr[e] * HH + h];
    float dn = dinv_all[f * NN + n];
    float v = dn * (acc + HL[(size_t)n * HH + h]) + bias[h];
    if (relu) v = fmaxf(v, 0.f);
    out[((size_t)f * NN + n) * HH + h] = v;
}

// ---------------- GRU gates ----------------
__global__ __launch_bounds__(256) void gru_gate_k(const float* __restrict__ gi,
                                                  const float* __restrict__ gh,
                                                  const float* __restrict__ b_ih,
                                                  const float* __restrict__ b_hh,
                                                  float* __restrict__ hgru) {
    int idx = blockIdx.x * blockDim.x + threadIdx.x;
    if (idx >= NN * HH) return;
    int h = idx & 127;
    size_t base = (size_t)(idx >> 7) * 384;
    float ir = gi[base + h]        + b_ih[h];
    float iz = gi[base + 128 + h]  + b_ih[128 + h];
    float in_ = gi[base + 256 + h] + b_ih[256 + h];
    float hr = gh[base + h]        + b_hh[h];
    float hz = gh[base + 128 + h]  + b_hh[128 + h];
    float hn = gh[base + 256 + h]  + b_hh[256 + h];
    float r = 1.f / (1.f + __expf(-(ir + hr)));
    float z = 1.f / (1.f + __expf(-(iz + hz)));
    float nn = tanhf(in_ + r * hn);
    float hp = hgru[idx];
    hgru[idx] = (1.f - z) * nn + z * hp;
}

// ---------------- decode ----------------
__global__ __launch_bounds__(256) void decode_k(const float* __restrict__ hgru,
                                                const int* __restrict__ pairs,
                                                float* __restrict__ out) {
    int gid = blockIdx.x * blockDim.x + threadIdx.x;
    int w = gid >> 6;
    int lane = threadIdx.x & 63;
    if (w >= PP) return;
    int s = pairs[w], d = pairs[PP + w];
    const float* zs = hgru + (size_t)s * HH;
    const float* zd = hgru + (size_t)d * HH;
    float acc = zs[lane] * zd[lane] + zs[lane + 64] * zd[lane + 64];
#pragma unroll
    for (int off = 32; off > 0; off >>= 1) acc += __shfl_down(acc, off);
    if (lane == 0) out[w] = acc;
}

// ---------------- orchestration ----------------
static inline size_t align256(size_t x) { return (x + 255) & ~(size_t)255; }

extern "C" void kernel_launch(void* const* d_in, const int* in_sizes, int n_in,
                              void* d_out, int out_size, void* d_ws, size_t ws_size,
                              hipStream_t stream) {
    const float* x_seq      = (const float*)d_in[0];
    const int*   edge_index = (const int*)d_in[1];
    const int*   edge_pairs = (const int*)d_in[2];
    const float* W1 = (const float*)d_in[3];
    const float* b1 = (const float*)d_in[4];
    const float* W2 = (const float*)d_in[5];
    const float* b2 = (const float*)d_in[6];
    const float* W3 = (const float*)d_in[7];
    const float* b3 = (const float*)d_in[8];
    const float* w_ih = (const float*)d_in[9];
    const float* w_hh = (const float*)d_in[10];
    const float* b_ih = (const float*)d_in[11];
    const float* b_hh = (const float*)d_in[12];

    char* p = (char*)d_ws;
    int*   cnt_all    = (int*)p;   p += align256((size_t)TT * NN * sizeof(int));
    int*   offs_all   = (int*)p;   p += align256((size_t)TT * (NN + 1) * sizeof(int));
    int*   cursor_all = (int*)p;   p += align256((size_t)TT * NN * sizeof(int));
    float* dinv_all   = (float*)p; p += align256((size_t)TT * NN * sizeof(float));
    int*   csr_all    = (int*)p;   p += align256((size_t)TT * EE * sizeof(int));
    float* HL   = (float*)p;       p += align256((size_t)TT * NN * HH * sizeof(float));  // 164 MB
    float* F    = (float*)p;       p += align256((size_t)TT * NN * HH * sizeof(float));  // 164 MB
    float* hgru = (float*)p;       p += align256((size_t)NN * HH * sizeof(float));
    float* gi   = (float*)p;       p += align256((size_t)NN * 3 * HH * sizeof(float));
    float* gh   = (float*)p;       p += align256((size_t)NN * 3 * HH * sizeof(float));
    unsigned short* W1h = (unsigned short*)p; p += align256(128 * 128 * 2);
    unsigned short* W1l = (unsigned short*)p; p += align256(128 * 128 * 2);
    unsigned short* W2h = (unsigned short*)p; p += align256(128 * 128 * 2);
    unsigned short* W2l = (unsigned short*)p; p += align256(128 * 128 * 2);
    unsigned short* W3h = (unsigned short*)p; p += align256(128 * 128 * 2);
    unsigned short* W3l = (unsigned short*)p; p += align256(128 * 128 * 2);
    unsigned short* wihh = (unsigned short*)p; p += align256(384 * 128 * 2);
    unsigned short* wihl = (unsigned short*)p; p += align256(384 * 128 * 2);
    unsigned short* whhh = (unsigned short*)p; p += align256(384 * 128 * 2);
    unsigned short* whhl = (unsigned short*)p; p += align256(384 * 128 * 2);

    hipMemsetAsync(hgru, 0, (size_t)NN * HH * sizeof(float), stream);
    hipMemsetAsync(cnt_all, 0, (size_t)TT * NN * sizeof(int), stream);

    wprep_t_k<<<64, 256, 0, stream>>>(W1, W1h, W1l);
    wprep_t_k<<<64, 256, 0, stream>>>(W2, W2h, W2l);
    wprep_t_k<<<64, 256, 0, stream>>>(W3, W3h, W3l);
    wprep_d_k<<<192, 256, 0, stream>>>(w_ih, wihh, wihl, 384 * 128);
    wprep_d_k<<<192, 256, 0, stream>>>(w_hh, whhh, whhl, 384 * 128);

    // batched CSR build for all frames
    dim3 ge((EE + 255) / 256, TT);
    dim3 gn((NN + 255) / 256, TT);
    hist_all_k<<<ge, 256, 0, stream>>>(edge_index, cnt_all);
    scan_all_k<<<TT, 1024, 0, stream>>>(cnt_all, offs_all);
    dinv_all_k<<<gn, 256, 0, stream>>>(cnt_all, dinv_all, cursor_all);
    fill_all_k<<<ge, 256, 0, stream>>>(edge_index, offs_all, cursor_all, csr_all);

    // batched GCN: 3 x (GEMM + agg) over all 16 frames
    const int MALL = TT * NN;                       // 320000
    dim3 gg((MALL + 63) / 64, 2);
    dim3 ga(NN, TT);
    gemm_bf16s<<<gg, 256, 0, stream>>>(x_seq, W1h, W1l, HL, dinv_all, MALL, 128);
    agg_all_k<<<ga, 128, 0, stream>>>(HL, csr_all, offs_all, dinv_all, b1, F, 1);
    gemm_bf16s<<<gg, 256, 0, stream>>>(F, W2h, W2l, HL, dinv_all, MALL, 128);
    agg_all_k<<<ga, 128, 0, stream>>>(HL, csr_all, offs_all, dinv_all, b2, F, 1);
    gemm_bf16s<<<gg, 256, 0, stream>>>(F, W3h, W3l, HL, dinv_all, MALL, 128);
    agg_all_k<<<ga, 128, 0, stream>>>(HL, csr_all, offs_all, dinv_all, b3, F, 0);

    // sequential GRU over time
    dim3 ggru((NN + 63) / 64, 12);
    for (int t = 0; t < TT; ++t) {
        gemm_gru_k<<<ggru, 256, 0, stream>>>(F + (size_t)t * NN * HH, hgru,
                                             wihh, wihl, whhh, whhl, gi, gh);
        gru_gate_k<<<(NN * HH + 255) / 256, 256, 0, stream>>>(gi, gh, b_ih, b_hh, hgru);
    }

    decode_k<<<(PP * 64 + 255) / 256, 256, 0, stream>>>(hgru, edge_pairs, (float*)d_out);
}